// Round 7
// baseline (300.590 us; speedup 1.0000x reference)
//
#include <hip/hip_runtime.h>
#include <math.h>

#define B_   4
#define T_   2048
#define D_   1024
#define H_   16
#define HD_  64
#define F_   128
#define C_   64
#define NCH  32
#define BT_  8192
#define BTD_ 8388608

typedef __bf16 bf16_t;
typedef __bf16 bf16x4 __attribute__((ext_vector_type(4)));
typedef __bf16 bf16x8 __attribute__((ext_vector_type(8)));
typedef float  f32x4  __attribute__((ext_vector_type(4)));

// async global->LDS, 16B/lane; LDS dest wave-uniform base + lane*16
#define GLD16(gp, lp)                                                      \
  __builtin_amdgcn_global_load_lds(                                       \
      (const __attribute__((address_space(1))) unsigned int*)(const void*)(gp), \
      (__attribute__((address_space(3))) unsigned int*)(void*)(lp), 16, 0, 0)

// row-dependent chunk swizzle (8-elem = 16B chunks)
__device__ __forceinline__ int swF(int f) { return (f & 7) ^ ((f >> 3) & 7); }

// ---------------------------------------------------------------------------
// K0: transpose 4 fp32 weights [K][N] -> bf16 [N][K]; z=4 converts hh weights
// ---------------------------------------------------------------------------
__global__ __launch_bounds__(256) void k_transpose_all(
    const float* __restrict__ w_q, const float* __restrict__ w_k,
    const float* __restrict__ w_v, const float* __restrict__ w_o,
    const float* __restrict__ hhqw, const float* __restrict__ hhkw,
    bf16_t* __restrict__ wqkvT, bf16_t* __restrict__ woT,
    bf16_t* __restrict__ hhbf) {
  const int z = blockIdx.z;
  const int tid = threadIdx.x;
  if (z == 4) {                       // hh weights: plain fp32->bf16 copy
    const int gid = blockIdx.y * 16 + blockIdx.x;
    if (gid < 32) {
      const int i = gid * 256 + tid;
      const float v = (i < 4096) ? hhqw[i] : hhkw[i - 4096];
      hhbf[i] = (__bf16)v;
    }
    return;
  }
  const float* w = (z == 0) ? w_q : (z == 1) ? w_k : (z == 2) ? w_v : w_o;
  bf16_t* wT = (z < 3) ? (wqkvT + (size_t)z * D_ * D_) : woT;
  __shared__ float tile[64][65];
  const int n0 = blockIdx.x * 64;
  const int k0 = blockIdx.y * 64;
#pragma unroll
  for (int g = 0; g < 4; ++g) {
    const int k = g * 16 + (tid >> 4);
    float4 v = *(const float4*)(w + (size_t)(k0 + k) * D_ + n0 + (tid & 15) * 4);
    tile[k][(tid & 15) * 4 + 0] = v.x;
    tile[k][(tid & 15) * 4 + 1] = v.y;
    tile[k][(tid & 15) * 4 + 2] = v.z;
    tile[k][(tid & 15) * 4 + 3] = v.w;
  }
  __syncthreads();
#pragma unroll
  for (int g = 0; g < 4; ++g) {
    const int n = g * 16 + (tid >> 4);
    bf16x4 o;
#pragma unroll
    for (int i = 0; i < 4; ++i) o[i] = (__bf16)tile[(tid & 15) * 4 + i][n];
    *(bf16x4*)(wT + (size_t)(n0 + n) * D_ + k0 + (tid & 15) * 4) = o;
  }
}

// ---------------------------------------------------------------------------
// K1: resid = hs + residual (fp32 -> d_out) ; x = rmsnorm(resid)*w (bf16)
// ---------------------------------------------------------------------------
__global__ __launch_bounds__(256) void k_add_rmsnorm(
    const float* __restrict__ hs, const float* __restrict__ res,
    const float* __restrict__ w, float* __restrict__ resid_out,
    bf16_t* __restrict__ x_out) {
  const int row = blockIdx.x;
  const size_t base = (size_t)row * D_;
  const int tid = threadIdx.x;
  float4 h4 = *(const float4*)(hs + base + tid * 4);
  float4 r4 = *(const float4*)(res + base + tid * 4);
  float4 s4;
  s4.x = h4.x + r4.x; s4.y = h4.y + r4.y;
  s4.z = h4.z + r4.z; s4.w = h4.w + r4.w;
  *(float4*)(resid_out + base + tid * 4) = s4;
  float ss = s4.x * s4.x + s4.y * s4.y + s4.z * s4.z + s4.w * s4.w;
#pragma unroll
  for (int off = 32; off > 0; off >>= 1) ss += __shfl_down(ss, off);
  __shared__ float red[4];
  if ((tid & 63) == 0) red[tid >> 6] = ss;
  __syncthreads();
  const float tot = red[0] + red[1] + red[2] + red[3];
  const float rstd = rsqrtf(tot * (1.0f / D_) + 1e-5f);
  float4 w4 = *(const float4*)(w + tid * 4);
  bf16x4 xo;
  xo[0] = (__bf16)(s4.x * rstd * w4.x);
  xo[1] = (__bf16)(s4.y * rstd * w4.y);
  xo[2] = (__bf16)(s4.z * rstd * w4.z);
  xo[3] = (__bf16)(s4.w * rstd * w4.w);
  *(bf16x4*)(x_out + base + tid * 4) = xo;
}

// ---------------------------------------------------------------------------
// K2: bf16 MFMA GEMM, 128x128 tile, BK=32, 2-phase dbuf + GLD16 staging.
// (at m97-structure ceiling; left unchanged this round)
// ---------------------------------------------------------------------------
template <int F32OUT>
__global__ __launch_bounds__(256) void k_gemm_mfma(
    const bf16_t* __restrict__ A, const bf16_t* __restrict__ BTb,
    void* __restrict__ Cb) {
  __shared__ bf16_t As[2][128 * 32];
  __shared__ bf16_t Bs[2][128 * 32];
  const int z = blockIdx.z;
  const bf16_t* BT = BTb + (size_t)z * (D_ * D_);
  const int tid = threadIdx.x;
  const int lane = tid & 63;
  const int wave = tid >> 6;
  const int bm = (blockIdx.x * 8 + (blockIdx.y & 7)) * 128;
  const int bn = (blockIdx.y >> 3) * 128;
  const int wm = (wave >> 1) * 64;
  const int wn = (wave & 1) * 64;
  const int r0 = wave * 32 + (lane >> 2);
  const int ssw = (((lane >> 2) & 3) ^ (lane >> 4));
  const int scol = (((lane & 3) ^ ssw) << 3);
  const bf16_t* ap0 = A + (size_t)(bm + r0) * D_ + scol;
  const bf16_t* ap1 = A + (size_t)(bm + r0 + 16) * D_ + scol;
  const bf16_t* bp0 = BT + (size_t)(bn + r0) * D_ + scol;
  const bf16_t* bp1 = BT + (size_t)(bn + r0 + 16) * D_ + scol;
  const int lb0 = wave * 1024;
  const int lb1 = wave * 1024 + 512;
  const int frow = lane & 15;
  const int lhi = lane >> 4;
  const int rsw = ((frow & 3) ^ ((frow >> 2) & 3));
  const int rcol = ((lhi ^ rsw) << 3);

  f32x4 acc[4][4] = {};
  GLD16(ap0, &As[0][lb0]);
  GLD16(ap1, &As[0][lb1]);
  GLD16(bp0, &Bs[0][lb0]);
  GLD16(bp1, &Bs[0][lb1]);
  __syncthreads();

  for (int k0 = 0; k0 < D_; k0 += 32) {
    const int cur = (k0 >> 5) & 1;
    if (k0 + 32 < D_) {
      const int nxt = cur ^ 1;
      GLD16(ap0 + k0 + 32, &As[nxt][lb0]);
      GLD16(ap1 + k0 + 32, &As[nxt][lb1]);
      GLD16(bp0 + k0 + 32, &Bs[nxt][lb0]);
      GLD16(bp1 + k0 + 32, &Bs[nxt][lb1]);
    }
    bf16x8 af[4], bq[4];
#pragma unroll
    for (int i = 0; i < 4; ++i) {
      af[i] = *(const bf16x8*)(&As[cur][(wm + i * 16 + frow) * 32 + rcol]);
      bq[i] = *(const bf16x8*)(&Bs[cur][(wn + i * 16 + frow) * 32 + rcol]);
    }
#pragma unroll
    for (int i = 0; i < 4; ++i)
#pragma unroll
      for (int j = 0; j < 4; ++j)
        acc[i][j] = __builtin_amdgcn_mfma_f32_16x16x32_bf16(af[i], bq[j],
                                                            acc[i][j], 0, 0, 0);
    __syncthreads();
  }

  const int crow0 = bm + wm + (lane >> 4) * 4;
  const int ccol0 = bn + wn + (lane & 15);
#pragma unroll
  for (int i = 0; i < 4; ++i)
#pragma unroll
    for (int j = 0; j < 4; ++j) {
      const size_t rb = (size_t)(crow0 + i * 16) * D_ + ccol0 + j * 16;
#pragma unroll
      for (int r = 0; r < 4; ++r) {
        if (F32OUT)
          ((float*)Cb)[rb + (size_t)r * D_] = acc[i][j][r];
        else
          ((bf16_t*)Cb + (size_t)z * ((size_t)BT_ * D_))[rb + (size_t)r * D_] =
              (__bf16)acc[i][j][r];
      }
    }
}

// ---------------------------------------------------------------------------
// K3: k-features + per-chunk kv state (no global feature writes).
// featT LDS [f=128][c=64] swizzled; kvT[d][f] = sum_c v[c,d]*feat[c,f].
// ---------------------------------------------------------------------------
__global__ __launch_bounds__(256) void k_featkv(
    const bf16_t* __restrict__ pk, const bf16_t* __restrict__ hhbf,
    const float* __restrict__ bk, const bf16_t* __restrict__ pv,
    bf16_t* __restrict__ kvout) {
  __shared__ bf16_t featT[128 * 64];
  __shared__ bf16_t vt[64 * 64];
  const int blk = blockIdx.x;
  const int n = blk % NCH;
  const int h = (blk / NCH) % H_;
  const int b = blk / (NCH * H_);
  const int tid = threadIdx.x;
  const int lane = tid & 63;
  const int wv = tid >> 6;
  const int l15 = lane & 15;
  const int lhi = lane >> 4;
  const bf16_t* wb = hhbf + 4096;    // k hedgehog weights

  // stage v^T early (loads in flight under feat MFMA)
#pragma unroll
  for (int g = 0; g < 2; ++g) {
    int i8 = g * 256 + tid;
    int m = i8 >> 3, d8 = (i8 & 7) * 8;
    bf16x8 v8 = *(const bf16x8*)(pv + (size_t)(b * T_ + n * 64 + m) * D_ +
                                 h * 64 + d8);
#pragma unroll
    for (int jj = 0; jj < 8; ++jj) {
      int d = d8 + jj;
      vt[d * 64 + (m ^ ((d & 7) << 3))] = v8[jj];
    }
  }

  // k-feats: y[t,e] = sum_d pk[t,d] W[e,d]
  const int trowA = n * 64 + wv * 16 + l15;
  bf16x8 pa[2];
#pragma unroll
  for (int s = 0; s < 2; ++s)
    pa[s] = *(const bf16x8*)(pk + (size_t)(b * T_ + trowA) * D_ + h * 64 +
                             s * 32 + lhi * 8);
  f32x4 acc[4] = {};
#pragma unroll
  for (int j = 0; j < 4; ++j)
#pragma unroll
    for (int s = 0; s < 2; ++s) {
      bf16x8 wf = *(const bf16x8*)(wb + (16 * j + l15) * 64 + s * 32 + lhi * 8);
      acc[j] = __builtin_amdgcn_mfma_f32_16x16x32_bf16(pa[s], wf, acc[j], 0, 0, 0);
    }
  float be[4];
#pragma unroll
  for (int j = 0; j < 4; ++j) be[j] = bk[16 * j + l15];

#pragma unroll
  for (int r = 0; r < 4; ++r) {
    float y[4];
#pragma unroll
    for (int j = 0; j < 4; ++j) y[j] = acc[j][r] + be[j];
    float m = fmaxf(fmaxf(fabsf(y[0]), fabsf(y[1])),
                    fmaxf(fabsf(y[2]), fabsf(y[3])));
#pragma unroll
    for (int o = 1; o < 16; o <<= 1) m = fmaxf(m, __shfl_xor(m, o));
    float e1[4], e2[4], s = 0.f;
#pragma unroll
    for (int j = 0; j < 4; ++j) {
      e1[j] = __expf(y[j] - m);
      e2[j] = __expf(-y[j] - m);
      s += e1[j] + e2[j];
    }
#pragma unroll
    for (int o = 1; o < 16; o <<= 1) s += __shfl_xor(s, o);
    const float inv = 1.0f / s;
    const int c = wv * 16 + lhi * 4 + r;
#pragma unroll
    for (int j = 0; j < 4; ++j) {
      const int f1 = 16 * j + l15, f2 = f1 + 64;
      featT[f1 * 64 + (((c >> 3) ^ swF(f1)) << 3) + (c & 7)] = (__bf16)(e1[j] * inv);
      featT[f2 * 64 + (((c >> 3) ^ swF(f2)) << 3) + (c & 7)] = (__bf16)(e2[j] * inv);
    }
  }
  __syncthreads();

  // kvT[d][f] via MFMA: A = vt rows d (c-contig), B = featT rows f
  const int drow = wv * 16 + l15;
  f32x4 a2[8] = {};
#pragma unroll
  for (int s = 0; s < 2; ++s) {
    const int c0 = s * 32 + lhi * 8;
    bf16x8 va = *(const bf16x8*)(vt + drow * 64 + (c0 ^ ((drow & 7) << 3)));
#pragma unroll
    for (int j = 0; j < 8; ++j) {
      const int fr = j * 16 + l15;
      bf16x8 kb = *(const bf16x8*)(featT + fr * 64 +
                                   ((((c0 >> 3) ^ swF(fr))) << 3));
      a2[j] = __builtin_amdgcn_mfma_f32_16x16x32_bf16(va, kb, a2[j], 0, 0, 0);
    }
  }
  bf16_t* ob = kvout + (size_t)blk * 8192;
#pragma unroll
  for (int j = 0; j < 8; ++j)
#pragma unroll
    for (int r = 0; r < 4; ++r) {
      int d = wv * 16 + lhi * 4 + r, f = j * 16 + l15;
      ob[d * 128 + f] = (__bf16)a2[j][r];
    }
}

// ---------------------------------------------------------------------------
// K5: exclusive prefix over chunk axis, register-resident, bf16x8/thread
// ---------------------------------------------------------------------------
__global__ __launch_bounds__(256) void k_cumsum_excl(bf16_t* __restrict__ kv) {
  const int bh = blockIdx.x >> 2;
  const int slice = blockIdx.x & 3;
  const int e = slice * 2048 + threadIdx.x * 8;
  bf16_t* base = kv + (size_t)bh * NCH * 8192 + e;
  bf16x8 vals[NCH];
#pragma unroll
  for (int n = 0; n < NCH; ++n) vals[n] = *(const bf16x8*)(base + (size_t)n * 8192);
  float run[8] = {};
#pragma unroll
  for (int n = 0; n < NCH; ++n) {
    bf16x8 o;
#pragma unroll
    for (int j = 0; j < 8; ++j) {
      o[j] = (__bf16)run[j];
      run[j] += (float)vals[n][j];
    }
    *(bf16x8*)(base + (size_t)n * 8192) = o;
  }
}

// ---------------------------------------------------------------------------
// K6: o = q @ S_excl + tril(q k^T) @ v, with q/k features RECOMPUTED in-block
// from pq/pk (saves 128MB of feature tensor traffic).
// featQ/featK LDS [c=64][f=128], chunk swizzle ^swF(c); st via GLD16.
// ---------------------------------------------------------------------------
__global__ __launch_bounds__(256) void k_attn_chunk(
    const bf16_t* __restrict__ pq,   // [BT,D]
    const bf16_t* __restrict__ pk,   // [BT,D]
    const bf16_t* __restrict__ pv,   // [BT,D]
    const bf16_t* __restrict__ hhbf, // [2][64][64] bf16
    const float* __restrict__ bq, const float* __restrict__ bk,
    const bf16_t* __restrict__ kvx,  // S_excl^T [B,H,N,HD,F]
    bf16_t* __restrict__ o_tmp) {    // [BT,D] (B,T,H,HD)
  __shared__ bf16_t featQ[64 * 128]; // 16KB
  __shared__ bf16_t featK[64 * 128]; // 16KB
  __shared__ bf16_t st[64 * 128];    // 16KB
  __shared__ bf16_t vt[64 * 64];     // 8KB
  __shared__ bf16_t scs[64 * 64];    // 8KB
  const int blk = blockIdx.x;
  const int n = blk % NCH;
  const int h = (blk / NCH) % H_;
  const int b = blk / (NCH * H_);
  const int tid = threadIdx.x;
  const int lane = tid & 63;
  const int wv = tid >> 6;
  const int l15 = lane & 15;
  const int lhi = lane >> 4;
  const bf16_t* kvb = kvx + (size_t)blk * 8192;

  // st staging via GLD16 (pre-swizzled source chunk: cc = pc ^ (row&7))
#pragma unroll
  for (int g = 0; g < 4; ++g) {
    const int cl = g * 256 + tid;
    const int row = cl >> 4, pc = cl & 15;
    const int cc = pc ^ (row & 7);
    const int lb = (g * 256 + wv * 64) * 8;
    GLD16(kvb + (size_t)row * F_ + cc * 8, st + lb);
  }
  // v^T staging
#pragma unroll
  for (int g = 0; g < 2; ++g) {
    int i8 = g * 256 + tid;
    int m = i8 >> 3, d8 = (i8 & 7) * 8;
    bf16x8 v8 = *(const bf16x8*)(pv + (size_t)(b * T_ + n * 64 + m) * D_ +
                                 h * 64 + d8);
#pragma unroll
    for (int jj = 0; jj < 8; ++jj) {
      int d = d8 + jj;
      vt[d * 64 + (m ^ ((d & 7) << 3))] = v8[jj];
    }
  }

  // recompute q-feats and k-feats for this chunk (wave-local rows)
  const size_t prow = (size_t)(b * T_ + n * 64 + wv * 16 + l15) * D_ + h * 64;
  bf16x8 paq[2], pak[2];
#pragma unroll
  for (int s = 0; s < 2; ++s) {
    paq[s] = *(const bf16x8*)(pq + prow + s * 32 + lhi * 8);
    pak[s] = *(const bf16x8*)(pk + prow + s * 32 + lhi * 8);
  }
  f32x4 aq[4] = {}, ak[4] = {};
#pragma unroll
  for (int j = 0; j < 4; ++j)
#pragma unroll
    for (int s = 0; s < 2; ++s) {
      bf16x8 wqf = *(const bf16x8*)(hhbf + (16 * j + l15) * 64 + s * 32 + lhi * 8);
      bf16x8 wkf = *(const bf16x8*)(hhbf + 4096 + (16 * j + l15) * 64 + s * 32 + lhi * 8);
      aq[j] = __builtin_amdgcn_mfma_f32_16x16x32_bf16(paq[s], wqf, aq[j], 0, 0, 0);
      ak[j] = __builtin_amdgcn_mfma_f32_16x16x32_bf16(pak[s], wkf, ak[j], 0, 0, 0);
    }
  float beq[4], bek[4];
#pragma unroll
  for (int j = 0; j < 4; ++j) {
    beq[j] = bq[16 * j + l15];
    bek[j] = bk[16 * j + l15];
  }
#pragma unroll
  for (int r = 0; r < 4; ++r) {
    const int c = wv * 16 + lhi * 4 + r;
#pragma unroll
    for (int qk = 0; qk < 2; ++qk) {
      float y[4];
#pragma unroll
      for (int j = 0; j < 4; ++j)
        y[j] = (qk ? ak[j][r] + bek[j] : aq[j][r] + beq[j]);
      float m = fmaxf(fmaxf(fabsf(y[0]), fabsf(y[1])),
                      fmaxf(fabsf(y[2]), fabsf(y[3])));
#pragma unroll
      for (int o = 1; o < 16; o <<= 1) m = fmaxf(m, __shfl_xor(m, o));
      float e1[4], e2[4], s = 0.f;
#pragma unroll
      for (int j = 0; j < 4; ++j) {
        e1[j] = __expf(y[j] - m);
        e2[j] = __expf(-y[j] - m);
        s += e1[j] + e2[j];
      }
#pragma unroll
      for (int o = 1; o < 16; o <<= 1) s += __shfl_xor(s, o);
      const float inv = (qk ? 1.0f : 0.08838834764831845f) / s;
      bf16_t* ft = qk ? featK : featQ;
#pragma unroll
      for (int j = 0; j < 4; ++j) {
        const int f1 = 16 * j + l15, f2 = f1 + 64;
        ft[c * 128 + (((f1 >> 3) ^ swF(c)) << 3) + (f1 & 7)] = (__bf16)(e1[j] * inv);
        ft[c * 128 + (((f2 >> 3) ^ swF(c)) << 3) + (f2 & 7)] = (__bf16)(e2[j] * inv);
      }
    }
  }
  __syncthreads();   // drains GLD16 vmcnt + all LDS writes

  // q-feat A-frags (wave-private rows of featQ)
  const int crow = wv * 16 + l15;
  bf16x8 qa[4];
#pragma unroll
  for (int s = 0; s < 4; ++s)
    qa[s] = *(const bf16x8*)(featQ + crow * 128 +
                             (((s * 4 + lhi) ^ swF(crow)) << 3));

  // scores = qfeat @ kfeat^T
  f32x4 accS[4] = {};
#pragma unroll
  for (int j = 0; j < 4; ++j) {
    const int mr = j * 16 + l15;
#pragma unroll
    for (int s = 0; s < 4; ++s) {
      bf16x8 kk = *(const bf16x8*)(featK + mr * 128 +
                                   (((s * 4 + lhi) ^ swF(mr)) << 3));
      accS[j] = __builtin_amdgcn_mfma_f32_16x16x32_bf16(qa[s], kk, accS[j], 0, 0, 0);
    }
  }
#pragma unroll
  for (int j = 0; j < 4; ++j)
#pragma unroll
    for (int r = 0; r < 4; ++r) {
      int c = wv * 16 + lhi * 4 + r;
      int m = j * 16 + l15;
      float v = (m <= c) ? accS[j][r] : 0.f;
      scs[c * 64 + (m ^ ((c & 7) << 3))] = (__bf16)v;
    }

  // inter = qfeat @ S_excl
  f32x4 acc[4] = {};
#pragma unroll
  for (int j = 0; j < 4; ++j) {
    const int dr = j * 16 + l15;
#pragma unroll
    for (int s = 0; s < 4; ++s) {
      bf16x8 sv = *(const bf16x8*)(st + dr * 128 +
                                   (((s * 4 + lhi) ^ (dr & 7)) << 3));
      acc[j] = __builtin_amdgcn_mfma_f32_16x16x32_bf16(qa[s], sv, acc[j], 0, 0, 0);
    }
  }

  // intra = sc @ v (scs same-wave rows; vt staged pre-barrier)
#pragma unroll
  for (int s2 = 0; s2 < 2; ++s2) {
    const int m0 = s2 * 32 + lhi * 8;
    bf16x8 sa = *(const bf16x8*)(scs + crow * 64 + (m0 ^ ((crow & 7) << 3)));
#pragma unroll
    for (int j = 0; j < 4; ++j) {
      const int dr = j * 16 + l15;
      bf16x8 vb = *(const bf16x8*)(vt + dr * 64 + (m0 ^ ((dr & 7) << 3)));
      acc[j] = __builtin_amdgcn_mfma_f32_16x16x32_bf16(sa, vb, acc[j], 0, 0, 0);
    }
  }

#pragma unroll
  for (int j = 0; j < 4; ++j)
#pragma unroll
    for (int r = 0; r < 4; ++r) {
      int c = wv * 16 + lhi * 4 + r, d = j * 16 + l15;
      o_tmp[(size_t)(b * T_ + n * 64 + c) * D_ + h * 64 + d] = (__bf16)acc[j][r];
    }
}

// ---------------------------------------------------------------------------
// Workspace (bytes):
//   [0,16M)    x bf16 [BT,D] -> reused as o_tmp
//   [16M,22M)  wqkvT bf16 [3][N][K]
//   [22M,24M)  woT bf16 [N][K]
//   [24M,88M)  (unused; former qf/kf)
//   [88M,136M) pq,pk,pvb bf16 [3][BT,D]
//   [136M,168M) kvT bf16 [B,H,N,HD,F]
//   [168M,+16K) hh weights bf16 [2][64][64]
// ---------------------------------------------------------------------------
extern "C" void kernel_launch(void* const* d_in, const int* in_sizes, int n_in,
                              void* d_out, int out_size, void* d_ws, size_t ws_size,
                              hipStream_t stream) {
  const float* hs   = (const float*)d_in[0];
  const float* res  = (const float*)d_in[1];
  const float* nw   = (const float*)d_in[2];
  const float* w_q  = (const float*)d_in[3];
  const float* w_k  = (const float*)d_in[4];
  const float* w_v  = (const float*)d_in[5];
  const float* w_o  = (const float*)d_in[6];
  const float* hhqw = (const float*)d_in[7];
  const float* hhqb = (const float*)d_in[8];
  const float* hhkw = (const float*)d_in[9];
  const float* hhkb = (const float*)d_in[10];

  float* out       = (float*)d_out;
  float* o_final   = out;
  float* resid_out = out + BTD_;

  char* wsb = (char*)d_ws;
  bf16_t* x_bf  = (bf16_t*)(wsb);
  bf16_t* wqkvT = (bf16_t*)(wsb + (16ull << 20));
  bf16_t* woT   = (bf16_t*)(wsb + (22ull << 20));
  bf16_t* pqkv  = (bf16_t*)(wsb + (88ull << 20));
  bf16_t* pq    = pqkv;
  bf16_t* pk    = pqkv + (size_t)BTD_;
  bf16_t* pvb   = pqkv + (size_t)2 * BTD_;
  bf16_t* kv    = (bf16_t*)(wsb + (136ull << 20));
  bf16_t* hhbf  = (bf16_t*)(wsb + (168ull << 20));
  bf16_t* o_tmp = x_bf;

  k_transpose_all<<<dim3(16, 16, 5), 256, 0, stream>>>(
      w_q, w_k, w_v, w_o, hhqw, hhkw, wqkvT, woT, hhbf);

  k_add_rmsnorm<<<BT_, 256, 0, stream>>>(hs, res, nw, resid_out, x_bf);

  k_gemm_mfma<0><<<dim3(8, 64, 3), 256, 0, stream>>>(x_bf, wqkvT, (void*)pqkv);

  k_featkv<<<2048, 256, 0, stream>>>(pk, hhbf, hhkb, pvb, kv);

  k_cumsum_excl<<<256, 256, 0, stream>>>(kv);

  k_attn_chunk<<<2048, 256, 0, stream>>>(pq, pk, pvb, hhbf, hhqb, hhkb,
                                         kv, o_tmp);

  k_gemm_mfma<1><<<dim3(8, 64, 1), 256, 0, stream>>>(o_tmp, woT, (void*)o_final);
}